// Round 3
// baseline (148.590 us; speedup 1.0000x reference)
//
#include <hip/hip_runtime.h>
#include <hip/hip_bf16.h>
#include <stdint.h>

typedef float    f32x4  __attribute__((ext_vector_type(4)));
typedef float    f32x16 __attribute__((ext_vector_type(16)));
typedef short    s16x8  __attribute__((ext_vector_type(8)));
typedef uint32_t u32x4  __attribute__((ext_vector_type(4)));

#define NB 8
#define NT 2048
#define NC 768
#define NH 64
#define LOG2E 1.4426950408889634f

__device__ __forceinline__ uint32_t f2bf1(float f) {
  union { float f; uint32_t u; } v; v.f = f;
  uint32_t u = v.u;
  return (u + 0x7fffu + ((u >> 16) & 1u)) >> 16;   // RNE
}
__device__ __forceinline__ uint32_t packbf2(float lo, float hi) {
  union { __hip_bfloat162 h; uint32_t u; } c;
  c.h = __float22bfloat162_rn(float2{lo, hi});     // v_cvt_pk_bf16_f32 on gfx950
  return c.u;
}

// ---------------- kernel 1: weights fp32 -> fused bf16 [192][768] (q:0-63,k:64-127,v:128-191)
__global__ __launch_bounds__(256) void wconv_kernel(
    const float* __restrict__ Wk, const float* __restrict__ Wq,
    const float* __restrict__ Wv, short* __restrict__ Wb)
{
  int idx = blockIdx.x * 256 + threadIdx.x;
  if (idx >= 192 * 768) return;
  int n = idx / 768;
  float v;
  if (n < 64)       v = Wq[idx];
  else if (n < 128) v = Wk[idx - 64 * 768];
  else              v = Wv[idx - 128 * 768];
  Wb[idx] = (short)f2bf1(v);
}

// ---------------- kernel 2: projection GEMM.
// Block = 256 thr (4 waves), 32 tokens. Whole x-tile staged bf16 into LDS ONCE
// (XOR-swizzled, conflict-free), then a barrier-free MFMA loop.
// Wave w: kh=w>>1 (K-half, 6 chunks of 64), nh=w&1 (N-half, 3 tiles of 32).
// q outputs are pre-scaled by log2(e) so attn can use exp2.
__global__ __launch_bounds__(256, 2) void proj_kernel(
    const float* __restrict__ x, const short* __restrict__ Wb,
    short* __restrict__ qb, short* __restrict__ kb, short* __restrict__ vTb)
{
  __shared__ char smem[49152 + 4096];
  short* ldsX   = (short*)smem;            // [12 chunk][32 tok][64 k] bf16, swizzled, 48 KB
  float* ldsAcc = (float*)smem;            // [32][192] fp32 (reused after compute barrier)
  short* ldsV   = (short*)(smem + 49152);  // [64][32] bf16

  const int tid  = threadIdx.x;
  const int lane = tid & 63;
  const int w    = tid >> 6;
  const int kh   = w >> 1;
  const int nh   = w & 1;
  const int col  = lane & 31;
  const int half = lane >> 5;
  const int t0   = blockIdx.x * 32;

  // ---- stage whole x-tile: thread -> (tok = tid>>3, g = tid&7), 12 chunks of 64 k
  {
    const int tok = tid >> 3;
    const int g   = tid & 7;
    const float* src = x + (size_t)(t0 + tok) * NC + g * 8;
    f32x4 st[12][2];
#pragma unroll
    for (int c = 0; c < 12; ++c) {
      st[c][0] = *(const f32x4*)(src + c * 64);
      st[c][1] = *(const f32x4*)(src + c * 64 + 4);
    }
    short* dst = ldsX + tok * 64 + ((g ^ (tok & 7)) << 3);
#pragma unroll
    for (int c = 0; c < 12; ++c) {
      u32x4 pw = {packbf2(st[c][0][0], st[c][0][1]), packbf2(st[c][0][2], st[c][0][3]),
                  packbf2(st[c][1][0], st[c][1][1]), packbf2(st[c][1][2], st[c][1][3])};
      *(u32x4*)(dst + c * 2048) = pw;
    }
  }
  __syncthreads();

  // ---- barrier-free MFMA loop
  f32x16 acc[3];
#pragma unroll
  for (int j = 0; j < 3; ++j)
#pragma unroll
    for (int e = 0; e < 16; ++e) acc[j][e] = 0.f;

#pragma unroll
  for (int c6 = 0; c6 < 6; ++c6) {
    const int c = kh * 6 + c6;
#pragma unroll
    for (int ks = 0; ks < 4; ++ks) {
      s16x8 af = *(const s16x8*)&ldsX[c * 2048 + col * 64 + (((ks * 2 + half) ^ (col & 7)) << 3)];
#pragma unroll
      for (int j = 0; j < 3; ++j) {
        int n = (nh * 3 + j) * 32 + col;
        s16x8 bf = *(const s16x8*)&Wb[(size_t)n * NC + c * 64 + ks * 16 + half * 8];
        acc[j] = __builtin_amdgcn_mfma_f32_32x32x16_bf16(af, bf, acc[j], 0, 0, 0);
      }
    }
  }

  // ---- merge K-halves through LDS (ldsAcc reuses the x-tile region)
  __syncthreads();
  if (kh == 0) {
#pragma unroll
    for (int j = 0; j < 3; ++j)
#pragma unroll
      for (int r = 0; r < 16; ++r) {
        int rd = (r & 3) + 8 * (r >> 2) + 4 * half;
        ldsAcc[rd * 192 + (nh * 3 + j) * 32 + col] = acc[j][r];
      }
  }
  __syncthreads();
  const int b  = t0 >> 11;
  const int tl = t0 & (NT - 1);
  if (kh == 1) {
#pragma unroll
    for (int j = 0; j < 3; ++j) {
      int nb = (nh * 3 + j) * 32;
#pragma unroll
      for (int r = 0; r < 16; ++r) {
        int rd = (r & 3) + 8 * (r >> 2) + 4 * half;
        float sum = acc[j][r] + ldsAcc[rd * 192 + nb + col];
        if (nb < 64) {
          qb[(size_t)(t0 + rd) * NH + nb + col] = (short)f2bf1(sum * LOG2E);
        } else if (nb < 128) {
          kb[(size_t)(t0 + rd) * NH + (nb - 64) + col] = (short)f2bf1(sum);
        } else {
          ldsV[(nb - 128 + col) * 32 + rd] = (short)f2bf1(sum);
        }
      }
    }
  }
  __syncthreads();
  {
    int h = tid >> 2, off = (tid & 3) * 8;
    *(s16x8*)&vTb[(size_t)(b * NH + h) * NT + tl + off] = *(const s16x8*)&ldsV[h * 32 + off];
  }
}

// ---------------- kernel 3: flash attention, S^T trick, 8-way in-block split-K.
// Block = 512 thr (8 waves), one 32-query tile; wave w owns key tiles [w*nT/8,(w+1)*nT/8).
// K/V fragments straight from global (L2-resident); log-domain softmax (q pre-scaled).
__global__ __launch_bounds__(512, 4) void attn_kernel(
    const short* __restrict__ qb, const short* __restrict__ kb,
    const short* __restrict__ vTb, float* __restrict__ out)
{
  __shared__ float ldsO[4][32][65];   // partial O^T slots (+1 pad)
  __shared__ float ldsM[4][32];
  __shared__ float ldsL[4][32];

  const int tid  = threadIdx.x;
  const int lane = tid & 63;
  const int w    = tid >> 6;
  const int col  = lane & 31;
  const int half = lane >> 5;
  const int b    = blockIdx.x >> 6;
  int qt = blockIdx.x & 63;
  if (blockIdx.x & 256) qt = 63 - qt;   // pair heavy+light q-tiles per CU
  const int q0 = qt * 32;
  const int nT = qt + 1;
  const int tBeg = (w * nT) >> 3;
  const int tEnd = ((w + 1) * nT) >> 3;

  s16x8 qf[4];
  {
    const short* qptr = qb + (size_t)(b * NT + q0 + col) * NH + half * 8;
#pragma unroll
    for (int ks = 0; ks < 4; ++ks) qf[ks] = *(const s16x8*)(qptr + ks * 16);
  }

  const short* kbase = kb  + (size_t)(b * NT + col) * NH + half * 8;
  const short* vbase = vTb + (size_t)(b * NH + col) * NT + half * 8;

  f32x16 oacc[2];
#pragma unroll
  for (int t = 0; t < 2; ++t)
#pragma unroll
    for (int e = 0; e < 16; ++e) oacc[t][e] = 0.f;

  float m = -1e30f, l = 0.f;

  s16x8 rk[4], rv[4];
  auto prefetch = [&](int t) {
#pragma unroll
    for (int ks = 0; ks < 4; ++ks)
      rk[ks] = *(const s16x8*)(kbase + (size_t)t * 32 * NH + ks * 16);
#pragma unroll
    for (int i = 0; i < 4; ++i)
      rv[i] = *(const s16x8*)(vbase + (size_t)(i >> 1) * 32 * NT + t * 32 + (i & 1) * 16);
  };
  if (tBeg < tEnd) prefetch(tBeg);

  for (int t = tBeg; t < tEnd; ++t) {
    s16x8 ck[4] = {rk[0], rk[1], rk[2], rk[3]};
    s16x8 cv[4] = {rv[0], rv[1], rv[2], rv[3]};
    if (t + 1 < tEnd) prefetch(t + 1);

    f32x16 s;
#pragma unroll
    for (int e = 0; e < 16; ++e) s[e] = 0.f;
#pragma unroll
    for (int ks = 0; ks < 4; ++ks)
      s = __builtin_amdgcn_mfma_f32_32x32x16_bf16(ck[ks], qf[ks], s, 0, 0, 0);

    if (t == nT - 1) {                 // diagonal tile: mask key > query
#pragma unroll
      for (int r = 0; r < 16; ++r) {
        int rd = (r & 3) + 8 * (r >> 2) + 4 * half;
        if (rd > col) s[r] = -1e30f;
      }
    }
    float vmax = s[0];
#pragma unroll
    for (int r = 1; r < 16; ++r) vmax = fmaxf(vmax, s[r]);
    vmax = fmaxf(vmax, __shfl_xor(vmax, 32));
    float mn    = fmaxf(m, vmax);
    float alpha = exp2f(m - mn);       // log-domain (q pre-scaled by log2e)
    float p[16];
    float rs = 0.f;
#pragma unroll
    for (int r = 0; r < 16; ++r) { p[r] = exp2f(s[r] - mn); rs += p[r]; }
    rs += __shfl_xor(rs, 32);
    l = l * alpha + rs;
    m = mn;
#pragma unroll
    for (int t2 = 0; t2 < 2; ++t2)
#pragma unroll
      for (int e = 0; e < 16; ++e) oacc[t2][e] *= alpha;

    uint32_t pw[8];
#pragma unroll
    for (int i = 0; i < 8; ++i) pw[i] = packbf2(p[2 * i], p[2 * i + 1]);
#pragma unroll
    for (int kc = 0; kc < 2; ++kc) {
      uint32_t s0 = half ? pw[4 * kc]     : pw[4 * kc + 2];
      uint32_t s1 = half ? pw[4 * kc + 1] : pw[4 * kc + 3];
      uint32_t r0 = __shfl_xor(s0, 32);
      uint32_t r1 = __shfl_xor(s1, 32);
      uint32_t w0 = half ? r0 : pw[4 * kc];
      uint32_t w1 = half ? r1 : pw[4 * kc + 1];
      uint32_t w2 = half ? pw[4 * kc + 2] : r0;
      uint32_t w3 = half ? pw[4 * kc + 3] : r1;
      union { u32x4 u; s16x8 v; } pf;
      pf.u = (u32x4){w0, w1, w2, w3};
#pragma unroll
      for (int ht = 0; ht < 2; ++ht)
        oacc[ht] = __builtin_amdgcn_mfma_f32_32x32x16_bf16(cv[ht * 2 + kc], pf.v, oacc[ht], 0, 0, 0);
    }
  }

  // ---- 3-stage tree merge of 8 per-wave partials through 4 LDS slots
  auto writeSlot = [&](int slot) {
    if (half == 0) { ldsM[slot][col] = m; ldsL[slot][col] = l; }
#pragma unroll
    for (int ht = 0; ht < 2; ++ht)
#pragma unroll
      for (int r = 0; r < 16; ++r) {
        int rd = (r & 3) + 8 * (r >> 2) + 4 * half;
        ldsO[slot][col][ht * 32 + rd] = oacc[ht][r];
      }
  };
  auto mergeFrom = [&](int slot) {
    float mb = ldsM[slot][col];
    float lb = ldsL[slot][col];
    float M2 = fmaxf(m, mb);
    float ca = exp2f(m - M2), cb = exp2f(mb - M2);
    l = ca * l + cb * lb;
    m = M2;
#pragma unroll
    for (int ht = 0; ht < 2; ++ht)
#pragma unroll
      for (int r = 0; r < 16; ++r) {
        int rd = (r & 3) + 8 * (r >> 2) + 4 * half;
        oacc[ht][r] = ca * oacc[ht][r] + cb * ldsO[slot][col][ht * 32 + rd];
      }
  };

  if (w >= 4) writeSlot(w - 4);
  __syncthreads();
  if (w < 4) mergeFrom(w);
  __syncthreads();
  if (w == 2 || w == 3) writeSlot(w - 2);
  __syncthreads();
  if (w < 2) mergeFrom(w);
  __syncthreads();
  if (w == 1) writeSlot(0);
  __syncthreads();
  if (w == 0) {
    mergeFrom(0);
    float inv = 1.0f / l;
#pragma unroll
    for (int ht = 0; ht < 2; ++ht)
#pragma unroll
      for (int r = 0; r < 16; ++r) {
        int rd = (r & 3) + 8 * (r >> 2) + 4 * half;
        ldsO[0][col][ht * 32 + rd] = oacc[ht][r] * inv;
      }
  }
  __syncthreads();
  {
    int q = tid >> 4, off = (tid & 15) * 4;
    *(f32x4*)(out + (size_t)(b * NT + q0 + q) * NH + off) = *(const f32x4*)&ldsO[0][q][off];
  }
}

extern "C" void kernel_launch(void* const* d_in, const int* in_sizes, int n_in,
                              void* d_out, int out_size, void* d_ws, size_t ws_size,
                              hipStream_t stream) {
  const float* x  = (const float*)d_in[0];
  const float* Wk = (const float*)d_in[1];
  const float* Wq = (const float*)d_in[2];
  const float* Wv = (const float*)d_in[3];
  float* out = (float*)d_out;

  char* ws = (char*)d_ws;
  short* Wb  = (short*)(ws);                          // 294912 B
  short* qb  = (short*)(ws + 524288);                 // 2 MB
  short* kb  = (short*)(ws + 524288 + 2097152);       // 2 MB
  short* vTb = (short*)(ws + 524288 + 2 * 2097152);   // 2 MB

  hipLaunchKernelGGL(wconv_kernel, dim3(576), dim3(256), 0, stream, Wk, Wq, Wv, Wb);
  hipLaunchKernelGGL(proj_kernel,  dim3(512), dim3(256), 0, stream, x, Wb, qb, kb, vTb);
  hipLaunchKernelGGL(attn_kernel,  dim3(512), dim3(512), 0, stream, qb, kb, vTb, out);
}

// Round 4
// 133.431 us; speedup vs baseline: 1.1136x; 1.1136x over previous
//
#include <hip/hip_runtime.h>
#include <hip/hip_bf16.h>
#include <stdint.h>

typedef float    f32x4  __attribute__((ext_vector_type(4)));
typedef float    f32x16 __attribute__((ext_vector_type(16)));
typedef short    s16x8  __attribute__((ext_vector_type(8)));
typedef uint32_t u32x4  __attribute__((ext_vector_type(4)));

#define NB 8
#define NT 2048
#define NC 768
#define NH 64
#define LOG2E 1.4426950408889634f

__device__ __forceinline__ uint32_t f2bf1(float f) {
  union { float f; uint32_t u; } v; v.f = f;
  uint32_t u = v.u;
  return (u + 0x7fffu + ((u >> 16) & 1u)) >> 16;   // RNE
}
__device__ __forceinline__ uint32_t packbf2(float lo, float hi) {
  union { __hip_bfloat162 h; uint32_t u; } c;
  c.h = __float22bfloat162_rn(float2{lo, hi});     // v_cvt_pk_bf16_f32
  return c.u;
}

// ---------------- kernel 1: weights fp32 -> fused bf16 [192][768] (q:0-63,k:64-127,v:128-191)
__global__ __launch_bounds__(256) void wconv_kernel(
    const float* __restrict__ Wk, const float* __restrict__ Wq,
    const float* __restrict__ Wv, short* __restrict__ Wb)
{
  int idx = blockIdx.x * 256 + threadIdx.x;
  if (idx >= 192 * 768) return;
  int n = idx / 768;
  float v;
  if (n < 64)       v = Wq[idx];
  else if (n < 128) v = Wk[idx - 64 * 768];
  else              v = Wv[idx - 128 * 768];
  Wb[idx] = (short)f2bf1(v);
}

// ---------------- kernel 2: projection GEMM, 8 waves (4-way K-split x 2-way N-split),
// no x-LDS (per-lane A-frag global loads; x read exactly once), unroll-2 register
// double-buffer on x and W. Outputs emitted in MFMA-FRAGMENT ORDER:
//   qf/kf_buf[b][tile][ks0..3][lane][8] : lane(col,half) holds X[tok=col][h=ks*16+half*8..+8]
//   vf_buf  [b][tile][i 0..3][lane][8] : lane(col,half) holds V^T[h=col+(i>>1)*32][key=(i&1)*16+half*8..+8]
// q pre-scaled by log2(e) for exp2 softmax.
__global__ __launch_bounds__(512, 2) void proj_kernel(
    const float* __restrict__ x, const short* __restrict__ Wb,
    short* __restrict__ qf_buf, short* __restrict__ kf_buf, short* __restrict__ vf_buf)
{
  __shared__ float slots[4 * 3072];          // 48 KB merge slots; overlaid by QT/KT/VT
  short* ldsQT = (short*)slots;              // [32 tok][68 h]  (2176 shorts)
  short* ldsKT = (short*)slots + 2176;       // [32 tok][68 h]
  short* ldsVT = (short*)slots + 4352;       // [64 h][34 key]

  const int tid  = threadIdx.x;
  const int lane = tid & 63;
  const int w    = tid >> 6;        // 0..7
  const int kh   = w >> 1;          // K quarter 0..3 (192 k each)
  const int nh   = w & 1;           // N half (96 n = 3 tiles of 32)
  const int col  = lane & 31;
  const int half = lane >> 5;
  const int t0   = blockIdx.x * 32;

  const float* xsrc = x + (size_t)(t0 + col) * NC + kh * 192 + half * 8;
  const short* w0 = Wb + (size_t)((nh * 3 + 0) * 32 + col) * NC + kh * 192 + half * 8;
  const short* w1 = w0 + 32 * NC;
  const short* w2 = w1 + 32 * NC;

  f32x16 acc[3];
#pragma unroll
  for (int j = 0; j < 3; ++j)
#pragma unroll
    for (int e = 0; e < 16; ++e) acc[j][e] = 0.f;

  f32x4 xA[2], xB[2];
  s16x8 wA[3], wB[3];
  auto loadS = [&](f32x4* xr, s16x8* wr, int ks) {
    xr[0] = *(const f32x4*)(xsrc + ks * 16);
    xr[1] = *(const f32x4*)(xsrc + ks * 16 + 4);
    wr[0] = *(const s16x8*)(w0 + ks * 16);
    wr[1] = *(const s16x8*)(w1 + ks * 16);
    wr[2] = *(const s16x8*)(w2 + ks * 16);
  };
  auto computeS = [&](f32x4* xr, s16x8* wr) {
    union { u32x4 u; s16x8 v; } af;
    af.u = (u32x4){packbf2(xr[0][0], xr[0][1]), packbf2(xr[0][2], xr[0][3]),
                   packbf2(xr[1][0], xr[1][1]), packbf2(xr[1][2], xr[1][3])};
    acc[0] = __builtin_amdgcn_mfma_f32_32x32x16_bf16(af.v, wr[0], acc[0], 0, 0, 0);
    acc[1] = __builtin_amdgcn_mfma_f32_32x32x16_bf16(af.v, wr[1], acc[1], 0, 0, 0);
    acc[2] = __builtin_amdgcn_mfma_f32_32x32x16_bf16(af.v, wr[2], acc[2], 0, 0, 0);
  };

  loadS(xA, wA, 0);
#pragma unroll
  for (int ks = 0; ks < 12; ks += 2) {
    loadS(xB, wB, ks + 1);
    computeS(xA, wA);
    if (ks + 2 < 12) loadS(xA, wA, ks + 2);
    computeS(xB, wB);
  }

  // ---- 3-stage K-merge tree through LDS (slots: [(kh-2)*2+nh] then [2+nh])
  if (kh >= 2) {
    float* sl = slots + ((kh - 2) * 2 + nh) * 3072;
#pragma unroll
    for (int j = 0; j < 3; ++j)
#pragma unroll
      for (int r = 0; r < 16; ++r) {
        int rd = (r & 3) + 8 * (r >> 2) + 4 * half;
        sl[rd * 96 + j * 32 + col] = acc[j][r];
      }
  }
  __syncthreads();
  if (kh < 2) {
    float* sl = slots + (kh * 2 + nh) * 3072;
#pragma unroll
    for (int j = 0; j < 3; ++j)
#pragma unroll
      for (int r = 0; r < 16; ++r) {
        int rd = (r & 3) + 8 * (r >> 2) + 4 * half;
        acc[j][r] += sl[rd * 96 + j * 32 + col];
      }
  }
  __syncthreads();
  if (kh == 1) {
    float* sl = slots + (2 + nh) * 3072;
#pragma unroll
    for (int j = 0; j < 3; ++j)
#pragma unroll
      for (int r = 0; r < 16; ++r) {
        int rd = (r & 3) + 8 * (r >> 2) + 4 * half;
        sl[rd * 96 + j * 32 + col] = acc[j][r];
      }
  }
  __syncthreads();
  if (kh == 0) {
    float* sl = slots + (2 + nh) * 3072;
#pragma unroll
    for (int j = 0; j < 3; ++j)
#pragma unroll
      for (int r = 0; r < 16; ++r) {
        int rd = (r & 3) + 8 * (r >> 2) + 4 * half;
        float sum = acc[j][r] + sl[rd * 96 + j * 32 + col];
        int nn = nh * 96 + j * 32 + col;
        if (nn < 64)        ldsQT[rd * 68 + nn]        = (short)f2bf1(sum * LOG2E);
        else if (nn < 128)  ldsKT[rd * 68 + (nn - 64)] = (short)f2bf1(sum);
        else                ldsVT[(nn - 128) * 34 + rd] = (short)f2bf1(sum);
      }
  }
  __syncthreads();

  // ---- fragment-order emit (fully coalesced 16B stores)
  {
    const int b  = t0 >> 11;
    const int kt = (t0 >> 5) & 63;
    const size_t base = ((size_t)(b * 64 + kt) * 4) * 512;   // shorts
    if (w < 4) {
      s16x8 vq = *(const s16x8*)&ldsQT[col * 68 + w * 16 + half * 8];
      *(s16x8*)&qf_buf[base + w * 512 + lane * 8] = vq;
      s16x8 vk = *(const s16x8*)&ldsKT[col * 68 + w * 16 + half * 8];
      *(s16x8*)&kf_buf[base + w * 512 + lane * 8] = vk;
    } else {
      int i = w - 4;
      s16x8 vv = *(const s16x8*)&ldsVT[(col + (i >> 1) * 32) * 34 + (i & 1) * 16 + half * 8];
      *(s16x8*)&vf_buf[base + i * 512 + lane * 8] = vv;
    }
  }
}

// ---------------- kernel 3: flash attention, S^T trick, 4-way in-block split-K,
// fragment-order K/V loads (contiguous 1KB per instruction), depth-2 double-buffer.
__global__ __launch_bounds__(256, 2) void attn_kernel(
    const short* __restrict__ qf_buf, const short* __restrict__ kf_buf,
    const short* __restrict__ vf_buf, float* __restrict__ out)
{
  __shared__ float ldsO[4][32][65];
  __shared__ float ldsM[4][32];
  __shared__ float ldsL[4][32];

  const int tid  = threadIdx.x;
  const int lane = tid & 63;
  const int w    = tid >> 6;
  const int col  = lane & 31;
  const int half = lane >> 5;
  const int b    = blockIdx.x >> 6;
  int qt = blockIdx.x & 63;
  if (blockIdx.x & 256) qt = 63 - qt;   // pair heavy+light q-tiles per CU
  const int q0 = qt * 32;
  const int nT = qt + 1;
  const int tBeg = (w * nT) >> 2;
  const int tEnd = ((w + 1) * nT) >> 2;

  s16x8 qf[4];
  {
    const short* qp = qf_buf + ((size_t)(b * 64 + qt) * 4) * 512 + lane * 8;
#pragma unroll
    for (int ks = 0; ks < 4; ++ks) qf[ks] = *(const s16x8*)(qp + ks * 512);
  }
  const short* kfb = kf_buf + (size_t)b * 64 * 2048 + lane * 8;
  const short* vfb = vf_buf + (size_t)b * 64 * 2048 + lane * 8;

  f32x16 oacc[2];
#pragma unroll
  for (int i = 0; i < 2; ++i)
#pragma unroll
    for (int e = 0; e < 16; ++e) oacc[i][e] = 0.f;
  float m = -1e30f, l = 0.f;

  s16x8 kA[4], vA[4], kB[4], vB[4];
  auto loadT = [&](s16x8* dk, s16x8* dv, int t) {
    const short* kp = kfb + (size_t)t * 2048;
    const short* vp = vfb + (size_t)t * 2048;
#pragma unroll
    for (int i = 0; i < 4; ++i) {
      dk[i] = *(const s16x8*)(kp + i * 512);
      dv[i] = *(const s16x8*)(vp + i * 512);
    }
  };
  auto body = [&](s16x8* ck, s16x8* cv, int t) {
    f32x16 s;
#pragma unroll
    for (int e = 0; e < 16; ++e) s[e] = 0.f;
#pragma unroll
    for (int ks = 0; ks < 4; ++ks)
      s = __builtin_amdgcn_mfma_f32_32x32x16_bf16(ck[ks], qf[ks], s, 0, 0, 0);

    if (t == nT - 1) {                 // diagonal tile: mask key > query
#pragma unroll
      for (int r = 0; r < 16; ++r) {
        int rd = (r & 3) + 8 * (r >> 2) + 4 * half;
        if (rd > col) s[r] = -1e30f;
      }
    }
    float vmax = s[0];
#pragma unroll
    for (int r = 1; r < 16; ++r) vmax = fmaxf(vmax, s[r]);
    vmax = fmaxf(vmax, __shfl_xor(vmax, 32));
    float mn    = fmaxf(m, vmax);
    float alpha = exp2f(m - mn);       // q pre-scaled by log2e
    float p[16];
    float rs = 0.f;
#pragma unroll
    for (int r = 0; r < 16; ++r) { p[r] = exp2f(s[r] - mn); rs += p[r]; }
    rs += __shfl_xor(rs, 32);
    l = l * alpha + rs;
    m = mn;
#pragma unroll
    for (int i = 0; i < 2; ++i)
#pragma unroll
      for (int e = 0; e < 16; ++e) oacc[i][e] *= alpha;

    uint32_t pw[8];
#pragma unroll
    for (int i = 0; i < 8; ++i) pw[i] = packbf2(p[2 * i], p[2 * i + 1]);
#pragma unroll
    for (int kc = 0; kc < 2; ++kc) {
      uint32_t s0 = half ? pw[4 * kc]     : pw[4 * kc + 2];
      uint32_t s1 = half ? pw[4 * kc + 1] : pw[4 * kc + 3];
      uint32_t r0 = __shfl_xor(s0, 32);
      uint32_t r1 = __shfl_xor(s1, 32);
      uint32_t w0 = half ? r0 : pw[4 * kc];
      uint32_t w1 = half ? r1 : pw[4 * kc + 1];
      uint32_t w2 = half ? pw[4 * kc + 2] : r0;
      uint32_t w3 = half ? pw[4 * kc + 3] : r1;
      union { u32x4 u; s16x8 v; } pf;
      pf.u = (u32x4){w0, w1, w2, w3};
#pragma unroll
      for (int ht = 0; ht < 2; ++ht)
        oacc[ht] = __builtin_amdgcn_mfma_f32_32x32x16_bf16(cv[ht * 2 + kc], pf.v, oacc[ht], 0, 0, 0);
    }
  };

  int t = tBeg;
  if (t < tEnd) loadT(kA, vA, t);
  if (t + 1 < tEnd) loadT(kB, vB, t + 1);
  for (; t + 1 < tEnd; t += 2) {
    body(kA, vA, t);
    if (t + 2 < tEnd) loadT(kA, vA, t + 2);
    body(kB, vB, t + 1);
    if (t + 3 < tEnd) loadT(kB, vB, t + 3);
  }
  if (t < tEnd) body(kA, vA, t);

  // ---- merge 4 per-wave partials
  if (half == 0) { ldsM[w][col] = m; ldsL[w][col] = l; }
#pragma unroll
  for (int ht = 0; ht < 2; ++ht)
#pragma unroll
    for (int r = 0; r < 16; ++r) {
      int rd = (r & 3) + 8 * (r >> 2) + 4 * half;
      ldsO[w][col][ht * 32 + rd] = oacc[ht][r];
    }
  __syncthreads();

  const int q  = tid >> 3;
  const int h0 = (tid & 7) * 8;
  float mv[4], lv[4];
#pragma unroll
  for (int i = 0; i < 4; ++i) { mv[i] = ldsM[i][q]; lv[i] = ldsL[i][q]; }
  float M = fmaxf(fmaxf(mv[0], mv[1]), fmaxf(mv[2], mv[3]));
  float cf[4], L = 0.f;
#pragma unroll
  for (int i = 0; i < 4; ++i) { cf[i] = exp2f(mv[i] - M); L += cf[i] * lv[i]; }
  float inv = 1.0f / L;
  float o[8];
#pragma unroll
  for (int j = 0; j < 8; ++j) {
    float a = 0.f;
#pragma unroll
    for (int i = 0; i < 4; ++i) a += cf[i] * ldsO[i][q][h0 + j];
    o[j] = a * inv;
  }
  float* obase = out + (size_t)(b * NT + q0 + q) * NH + h0;
  *(f32x4*)obase       = (f32x4){o[0], o[1], o[2], o[3]};
  *(f32x4*)(obase + 4) = (f32x4){o[4], o[5], o[6], o[7]};
}

extern "C" void kernel_launch(void* const* d_in, const int* in_sizes, int n_in,
                              void* d_out, int out_size, void* d_ws, size_t ws_size,
                              hipStream_t stream) {
  const float* x  = (const float*)d_in[0];
  const float* Wk = (const float*)d_in[1];
  const float* Wq = (const float*)d_in[2];
  const float* Wv = (const float*)d_in[3];
  float* out = (float*)d_out;

  char* ws = (char*)d_ws;
  short* Wb  = (short*)(ws);                          // 294912 B
  short* qfb = (short*)(ws + (512 << 10));            // 2 MB frag-order Q
  short* kfb = (short*)(ws + (512 << 10) + (2 << 20));// 2 MB frag-order K
  short* vfb = (short*)(ws + (512 << 10) + (4 << 20));// 2 MB frag-order V

  hipLaunchKernelGGL(wconv_kernel, dim3(576), dim3(256), 0, stream, Wk, Wq, Wv, Wb);
  hipLaunchKernelGGL(proj_kernel,  dim3(512), dim3(512), 0, stream, x, Wb, qfb, kfb, vfb);
  hipLaunchKernelGGL(attn_kernel,  dim3(512), dim3(256), 0, stream, qfb, kfb, vfb, out);
}

// Round 5
// 115.635 us; speedup vs baseline: 1.2850x; 1.1539x over previous
//
#include <hip/hip_runtime.h>
#include <hip/hip_bf16.h>
#include <stdint.h>

typedef float    f32x4  __attribute__((ext_vector_type(4)));
typedef float    f32x16 __attribute__((ext_vector_type(16)));
typedef short    s16x8  __attribute__((ext_vector_type(8)));
typedef uint32_t u32x4  __attribute__((ext_vector_type(4)));
typedef uint32_t u32x2  __attribute__((ext_vector_type(2)));

#define NB 8
#define NT 2048
#define NC 768
#define NH 64
#define LOG2E 1.4426950408889634f

__device__ __forceinline__ uint32_t f2bf1(float f) {
  union { float f; uint32_t u; } v; v.f = f;
  uint32_t u = v.u;
  return (u + 0x7fffu + ((u >> 16) & 1u)) >> 16;   // RNE
}
__device__ __forceinline__ uint32_t packbf2(float lo, float hi) {
  union { __hip_bfloat162 h; uint32_t u; } c;
  c.h = __float22bfloat162_rn(float2{lo, hi});
  return c.u;
}
__device__ __forceinline__ float bf2f(short s) {
  union { float f; uint32_t u; } v; v.u = ((uint32_t)(uint16_t)s) << 16; return v.f;
}

// ---------------- kernel 1: weights fp32 -> bf16 in MFMA B-FRAGMENT order.
// Wf[((nt*48 + ks)*64 + lane)*8 + j] = W[n = nt*32+col][k = ks*16 + half*8 + j]
// n<64: Wq (scaled by log2e, folds softmax exp2), 64-127: Wk, 128-191: Wv.
__global__ __launch_bounds__(256) void wconv_kernel(
    const float* __restrict__ Wk, const float* __restrict__ Wq,
    const float* __restrict__ Wv, short* __restrict__ Wf)
{
  int f = blockIdx.x * 256 + threadIdx.x;       // 18432 frags
  int lane = f & 63;
  int rest = f >> 6;
  int ks = rest % 48;
  int nt = rest / 48;
  int col = lane & 31, half = lane >> 5;
  int n = nt * 32 + col;
  int k = ks * 16 + half * 8;
  const float* src;
  float sc = 1.0f;
  if (n < 64)       { src = Wq + (size_t)n * NC + k; sc = LOG2E; }
  else if (n < 128) { src = Wk + (size_t)(n - 64) * NC + k; }
  else              { src = Wv + (size_t)(n - 128) * NC + k; }
  f32x4 a = *(const f32x4*)src;
  f32x4 b = *(const f32x4*)(src + 4);
  u32x4 o = {packbf2(a[0] * sc, a[1] * sc), packbf2(a[2] * sc, a[3] * sc),
             packbf2(b[0] * sc, b[1] * sc), packbf2(b[2] * sc, b[3] * sc)};
  *(u32x4*)&Wf[(size_t)f * 8] = o;
}

// ---------------- kernel 2: projection GEMM. Block = 256 thr (4 waves), 32 tokens.
// Coalesced x reads -> swizzled bf16 LDS tile (48 KB) -> ds_read_b128 A-frags.
// W loaded in fragment order (fully coalesced, L2-resident). 4-way K-split, LDS merge.
// NO divergent global loads anywhere.
__global__ __launch_bounds__(256, 2) void proj_kernel(
    const float* __restrict__ x, const short* __restrict__ Wf,
    short* __restrict__ qf_buf, short* __restrict__ kf_buf, short* __restrict__ vf_buf)
{
  __shared__ char smem[49152];
  short* ldsX  = (short*)smem;                 // [32 tok][96 grp of 8] swizzled
  float* slot0 = (float*)smem;                 // [32][192] f32 (reused)
  float* slot1 = (float*)(smem + 24576);
  short* ldsQT = (short*)(smem + 24576);       // [32][68]  (inside slot1, used after it's free)
  short* ldsKT = ldsQT + 2176;                 // [32][68]
  short* ldsVT = ldsQT + 4352;                 // [64][34]

  const int tid  = threadIdx.x;
  const int lane = tid & 63;
  const int w    = tid >> 6;
  const int col  = lane & 31;
  const int half = lane >> 5;
  const int t0   = blockIdx.x * 32;

  // ---- stage: coalesced fp32 reads, pack bf16, swizzled LDS store
  {
    const int tok = tid >> 3, g = tid & 7;
    const float* src = x + (size_t)(t0 + tok) * NC + g * 8;
    short* drow = ldsX + tok * 768;
#pragma unroll
    for (int i = 0; i < 12; ++i) {
      f32x4 a = *(const f32x4*)(src + i * 64);
      f32x4 b = *(const f32x4*)(src + i * 64 + 4);
      int grp = g + i * 8;
      int swz = (grp & ~7) | ((grp ^ tok) & 7);
      u32x4 o = {packbf2(a[0], a[1]), packbf2(a[2], a[3]),
                 packbf2(b[0], b[1]), packbf2(b[2], b[3])};
      *(u32x4*)&drow[swz * 8] = o;
    }
  }
  __syncthreads();

  // ---- compute: wave w owns K-quarter (ks = 12w .. 12w+11), all 6 n-tiles
  f32x16 acc[6];
#pragma unroll
  for (int j = 0; j < 6; ++j)
#pragma unroll
    for (int e = 0; e < 16; ++e) acc[j][e] = 0.f;

  const short* wbase = Wf + lane * 8;
  auto loadW = [&](s16x8* d, int ks) {
#pragma unroll
    for (int nt = 0; nt < 6; ++nt)
      d[nt] = *(const s16x8*)(wbase + ((size_t)(nt * 48 + ks) << 9));
  };
  auto loadA = [&](int ks) -> s16x8 {
    int grp = ks * 2 + half;
    int swz = (grp & ~7) | ((grp ^ col) & 7);
    return *(const s16x8*)&ldsX[col * 768 + swz * 8];
  };

  {
    const int ks0 = w * 12;
    s16x8 wA[6], wB[6], aA, aB;
    loadW(wA, ks0);
    aA = loadA(ks0);
#pragma unroll
    for (int s = 0; s < 12; s += 2) {
      loadW(wB, ks0 + s + 1);
      aB = loadA(ks0 + s + 1);
#pragma unroll
      for (int nt = 0; nt < 6; ++nt)
        acc[nt] = __builtin_amdgcn_mfma_f32_32x32x16_bf16(aA, wA[nt], acc[nt], 0, 0, 0);
      if (s + 2 < 12) { loadW(wA, ks0 + s + 2); aA = loadA(ks0 + s + 2); }
#pragma unroll
      for (int nt = 0; nt < 6; ++nt)
        acc[nt] = __builtin_amdgcn_mfma_f32_32x32x16_bf16(aB, wB[nt], acc[nt], 0, 0, 0);
    }
  }

  // ---- 4-way K-merge tree through LDS (slots reuse ldsX region)
  auto putSlot = [&](float* sl) {
#pragma unroll
    for (int nt = 0; nt < 6; ++nt)
#pragma unroll
      for (int r = 0; r < 16; ++r) {
        int rd = (r & 3) + 8 * (r >> 2) + 4 * half;
        sl[rd * 192 + nt * 32 + col] = acc[nt][r];
      }
  };
  auto addSlot = [&](float* sl) {
#pragma unroll
    for (int nt = 0; nt < 6; ++nt)
#pragma unroll
      for (int r = 0; r < 16; ++r) {
        int rd = (r & 3) + 8 * (r >> 2) + 4 * half;
        acc[nt][r] += sl[rd * 192 + nt * 32 + col];
      }
  };

  __syncthreads();                 // compute done; ldsX free
  if (w >= 2) putSlot(w == 2 ? slot0 : slot1);
  __syncthreads();
  if (w < 2) addSlot(w == 0 ? slot0 : slot1);
  __syncthreads();
  if (w == 1) putSlot(slot0);
  __syncthreads();
  if (w == 0) {
    addSlot(slot0);
    // final sums -> transposed bf16 staging for fragment-order emit
#pragma unroll
    for (int nt = 0; nt < 6; ++nt) {
      int n = nt * 32 + col;
#pragma unroll
      for (int r = 0; r < 16; ++r) {
        int rd = (r & 3) + 8 * (r >> 2) + 4 * half;
        short v = (short)f2bf1(acc[nt][r]);
        if (n < 64)       ldsQT[rd * 68 + n] = v;
        else if (n < 128) ldsKT[rd * 68 + (n - 64)] = v;
        else              ldsVT[(n - 128) * 34 + rd] = v;
      }
    }
  }
  __syncthreads();

  // ---- fragment-order emit (coalesced 16B stores), wave w = frag index
  {
    const int b  = t0 >> 11;
    const int kt = (t0 >> 5) & 63;
    const size_t base = (size_t)(b * 64 + kt) * 2048;   // shorts
    s16x8 vq = *(const s16x8*)&ldsQT[col * 68 + w * 16 + half * 8];
    *(s16x8*)&qf_buf[base + w * 512 + lane * 8] = vq;
    s16x8 vk = *(const s16x8*)&ldsKT[col * 68 + w * 16 + half * 8];
    *(s16x8*)&kf_buf[base + w * 512 + lane * 8] = vk;
    s16x8 vv = *(const s16x8*)&ldsVT[(col + (w >> 1) * 32) * 34 + (w & 1) * 16 + half * 8];
    *(s16x8*)&vf_buf[base + w * 512 + lane * 8] = vv;
  }
}

// ---------------- kernel 3: flash attention. Block = 512 thr (8 waves) owns the
// q-tile PAIR (qt, 63-qt) = exactly 65 key-tiles -> perfect balance by construction.
// Heavy group (nH waves) -> qt=63-pr, light (8-nH) -> qt=pr. b = blk&7 for XCD L2 locality.
__global__ __launch_bounds__(512, 2) void attn_kernel(
    const short* __restrict__ qf_buf, const short* __restrict__ kf_buf,
    const short* __restrict__ vf_buf, float* __restrict__ out)
{
  __shared__ short ldsOb[8][32][72];   // bf16 O^T partials per wave slot
  __shared__ float ldsM[8][32];
  __shared__ float ldsL[8][32];

  const int tid  = threadIdx.x;
  const int lane = tid & 63;
  const int w    = tid >> 6;
  const int col  = lane & 31;
  const int half = lane >> 5;
  const int b    = blockIdx.x & 7;
  const int pr   = blockIdx.x >> 3;        // 0..31
  const int qtL = pr, qtH = 63 - pr;
  const int Hn = 64 - pr, Ln = pr + 1;     // tiles per q-tile
  int nH = (8 * Hn + 32) / 65;
  if (nH < 1) nH = 1;
  if (nH > 7) nH = 7;
  const int nL = 8 - nH;

  int qt, tBeg, tEnd;
  if (w < nH) { qt = qtH; tBeg = (w * Hn) / nH; tEnd = ((w + 1) * Hn) / nH; }
  else        { int wl = w - nH; qt = qtL; tBeg = (wl * Ln) / nL; tEnd = ((wl + 1) * Ln) / nL; }

  s16x8 qf[4];
  {
    const short* qp = qf_buf + (size_t)(b * 64 + qt) * 2048 + lane * 8;
#pragma unroll
    for (int ks = 0; ks < 4; ++ks) qf[ks] = *(const s16x8*)(qp + ks * 512);
  }
  const short* kfb = kf_buf + (size_t)b * 64 * 2048 + lane * 8;
  const short* vfb = vf_buf + (size_t)b * 64 * 2048 + lane * 8;

  f32x16 oacc[2];
#pragma unroll
  for (int i = 0; i < 2; ++i)
#pragma unroll
    for (int e = 0; e < 16; ++e) oacc[i][e] = 0.f;
  float m = -1e30f, l = 0.f;

  s16x8 kA[4], vA[4], kB[4], vB[4];
  auto loadT = [&](s16x8* dk, s16x8* dv, int t) {
    const short* kp = kfb + (size_t)t * 2048;
    const short* vp = vfb + (size_t)t * 2048;
#pragma unroll
    for (int i = 0; i < 4; ++i) {
      dk[i] = *(const s16x8*)(kp + i * 512);
      dv[i] = *(const s16x8*)(vp + i * 512);
    }
  };
  auto body = [&](s16x8* ck, s16x8* cv, int t) {
    f32x16 s;
#pragma unroll
    for (int e = 0; e < 16; ++e) s[e] = 0.f;
#pragma unroll
    for (int ks = 0; ks < 4; ++ks)
      s = __builtin_amdgcn_mfma_f32_32x32x16_bf16(ck[ks], qf[ks], s, 0, 0, 0);

    if (t == qt) {                     // diagonal tile: mask key > query
#pragma unroll
      for (int r = 0; r < 16; ++r) {
        int rd = (r & 3) + 8 * (r >> 2) + 4 * half;
        if (rd > col) s[r] = -1e30f;
      }
    }
    float vmax = s[0];
#pragma unroll
    for (int r = 1; r < 16; ++r) vmax = fmaxf(vmax, s[r]);
    vmax = fmaxf(vmax, __shfl_xor(vmax, 32));
    float mn    = fmaxf(m, vmax);
    float alpha = exp2f(m - mn);       // log2e folded into Wq
    float p[16];
    float rs = 0.f;
#pragma unroll
    for (int r = 0; r < 16; ++r) { p[r] = exp2f(s[r] - mn); rs += p[r]; }
    rs += __shfl_xor(rs, 32);
    l = l * alpha + rs;
    m = mn;
#pragma unroll
    for (int i = 0; i < 2; ++i)
#pragma unroll
      for (int e = 0; e < 16; ++e) oacc[i][e] *= alpha;

    uint32_t pw[8];
#pragma unroll
    for (int i = 0; i < 8; ++i) pw[i] = packbf2(p[2 * i], p[2 * i + 1]);
#pragma unroll
    for (int kc = 0; kc < 2; ++kc) {
      uint32_t s0 = half ? pw[4 * kc]     : pw[4 * kc + 2];
      uint32_t s1 = half ? pw[4 * kc + 1] : pw[4 * kc + 3];
      uint32_t r0 = __shfl_xor(s0, 32);
      uint32_t r1 = __shfl_xor(s1, 32);
      uint32_t w0 = half ? r0 : pw[4 * kc];
      uint32_t w1 = half ? r1 : pw[4 * kc + 1];
      uint32_t w2 = half ? pw[4 * kc + 2] : r0;
      uint32_t w3 = half ? pw[4 * kc + 3] : r1;
      union { u32x4 u; s16x8 v; } pf;
      pf.u = (u32x4){w0, w1, w2, w3};
#pragma unroll
      for (int ht = 0; ht < 2; ++ht)
        oacc[ht] = __builtin_amdgcn_mfma_f32_32x32x16_bf16(cv[ht * 2 + kc], pf.v, oacc[ht], 0, 0, 0);
    }
  };

  int t = tBeg;
  if (t < tEnd) loadT(kA, vA, t);
  if (t + 1 < tEnd) loadT(kB, vB, t + 1);
  for (; t + 1 < tEnd; t += 2) {
    body(kA, vA, t);
    if (t + 2 < tEnd) loadT(kA, vA, t + 2);
    body(kB, vB, t + 1);
    if (t + 3 < tEnd) loadT(kB, vB, t + 3);
  }
  if (t < tEnd) body(kA, vA, t);

  // ---- write per-wave partials (bf16 O^T, packed 8B stores)
  if (half == 0) { ldsM[w][col] = m; ldsL[w][col] = l; }
#pragma unroll
  for (int ht = 0; ht < 2; ++ht)
#pragma unroll
    for (int u = 0; u < 4; ++u) {
      int h = ht * 32 + 8 * u + 4 * half;
      u32x2 pk = {packbf2(oacc[ht][4 * u + 0], oacc[ht][4 * u + 1]),
                  packbf2(oacc[ht][4 * u + 2], oacc[ht][4 * u + 3])};
      *(u32x2*)&ldsOb[w][col][h] = pk;
    }
  __syncthreads();

  // ---- merge: 512 thr = 2 segs x 32 rows x 8 h-chunks
  {
    const int seg = tid >> 8;            // 0 = heavy, 1 = light
    const int rr  = (tid >> 3) & 31;
    const int h0  = (tid & 7) * 8;
    const int s0  = seg ? nH : 0;
    const int s1  = seg ? 8 : nH;
    float M = -1e30f;
    for (int s = s0; s < s1; ++s) M = fmaxf(M, ldsM[s][rr]);
    float Ls = 0.f;
    float o[8];
#pragma unroll
    for (int j = 0; j < 8; ++j) o[j] = 0.f;
    for (int s = s0; s < s1; ++s) {
      float cf = exp2f(ldsM[s][rr] - M);
      Ls += cf * ldsL[s][rr];
      s16x8 raw = *(const s16x8*)&ldsOb[s][rr][h0];
#pragma unroll
      for (int j = 0; j < 8; ++j) o[j] += cf * bf2f(raw[j]);
    }
    float inv = 1.0f / Ls;
    int qrow = (seg ? qtL : qtH) * 32 + rr;
    float* ob = out + (size_t)(b * NT + qrow) * NH + h0;
    *(f32x4*)ob       = (f32x4){o[0] * inv, o[1] * inv, o[2] * inv, o[3] * inv};
    *(f32x4*)(ob + 4) = (f32x4){o[4] * inv, o[5] * inv, o[6] * inv, o[7] * inv};
  }
}

extern "C" void kernel_launch(void* const* d_in, const int* in_sizes, int n_in,
                              void* d_out, int out_size, void* d_ws, size_t ws_size,
                              hipStream_t stream) {
  const float* x  = (const float*)d_in[0];
  const float* Wk = (const float*)d_in[1];
  const float* Wq = (const float*)d_in[2];
  const float* Wv = (const float*)d_in[3];
  float* out = (float*)d_out;

  char* ws = (char*)d_ws;
  short* Wf  = (short*)(ws);                           // 294912 B frag-order W
  short* qfb = (short*)(ws + (512 << 10));             // 2 MB frag-order Q
  short* kfb = (short*)(ws + (512 << 10) + (2 << 20)); // 2 MB frag-order K
  short* vfb = (short*)(ws + (512 << 10) + (4 << 20)); // 2 MB frag-order V

  hipLaunchKernelGGL(wconv_kernel, dim3(72),  dim3(256), 0, stream, Wk, Wq, Wv, Wf);
  hipLaunchKernelGGL(proj_kernel,  dim3(512), dim3(256), 0, stream, x, Wf, qfb, kfb, vfb);
  hipLaunchKernelGGL(attn_kernel,  dim3(256), dim3(512), 0, stream, qfb, kfb, vfb, out);
}